// Round 7
// baseline (804.470 us; speedup 1.0000x reference)
//
#include <hip/hip_runtime.h>
#include <hip/hip_bf16.h>
#include <cstddef>

// Problem constants (fixed by the reference)
constexpr int T_ = 512;
constexpr int B_ = 8;
constexpr int H_ = 256;
constexpr int V_ = 32000;
constexpr int L_ = 3;
constexpr int M_ = T_ * B_;   // 4096 rows in all GEMMs

typedef __attribute__((ext_vector_type(8))) short short8;
typedef __attribute__((ext_vector_type(4))) float floatx4;

// fp32 -> bf16 round-to-nearest-even
__device__ __forceinline__ unsigned short f2bf(float f) {
    unsigned u = __float_as_uint(f);
    u += 0x7fffu + ((u >> 16) & 1u);
    return (unsigned short)(u >> 16);
}

// async global->LDS, 16B per lane; LDS dest = wave-uniform base + lane*16
__device__ __forceinline__ void gl_lds16(const void* g, void* l) {
    __builtin_amdgcn_global_load_lds((__attribute__((address_space(1))) void*)g,
                                     (__attribute__((address_space(3))) void*)l,
                                     16, 0, 0);
}

// ---------------------------------------------------------------------------
// Embed: h_bf[t,b,:] = bf16(token_emb[tokens[t,b],:] + pos_emb[t,:])
// ---------------------------------------------------------------------------
__global__ __launch_bounds__(256) void embed_kernel(
    const int* __restrict__ tokens, const float* __restrict__ temb,
    const float* __restrict__ pemb, unsigned short* __restrict__ hb)
{
    const int idx = blockIdx.x * 256 + threadIdx.x;      // 0 .. T*B*H/4-1
    const int h4 = idx & (H_ / 4 - 1);
    const int tb = idx >> 6;
    const int b  = tb & (B_ - 1);
    const int t  = tb >> 3;
    const int tok = tokens[t * B_ + b];
    const float4 e = *(const float4*)&temb[(size_t)tok * H_ + h4 * 4];
    const float4 p = *(const float4*)&pemb[(size_t)t * H_ + h4 * 4];
    ushort4 r;
    r.x = f2bf(e.x + p.x); r.y = f2bf(e.y + p.y);
    r.z = f2bf(e.z + p.z); r.w = f2bf(e.w + p.w);
    *(ushort4*)&hb[(size_t)idx * 4] = r;
}

// ===========================================================================
// Parallel chunked leaky scan (linear recurrence; chunk-local + carry apply).
// Spike margin ~0.9 vs the ~1e-7 reordering delta -> no spike flips.
// ===========================================================================
constexpr int CH_ = 32;
constexpr int NT_ = T_ / CH_;          // 16 chunks
constexpr int TS_ = B_ * H_;           // 2048: t-stride in [T][B][H]

__global__ __launch_bounds__(256) void scan_local_kernel(
    const float* __restrict__ cur, const float* __restrict__ beta_l,
    float* __restrict__ mloc)
{
    const int c = blockIdx.x, b = blockIdx.y, h = threadIdx.x;
    const float bt = beta_l[h];
    const size_t off = ((size_t)(c * CH_) * B_ + b) * H_ + h;
    const float* p = cur + off;
    float* q = mloc + off;
    float mem = 0.0f;
    #pragma unroll
    for (int tt = 0; tt < CH_; ++tt) {
        mem = fmaf(bt, mem, p[(size_t)tt * TS_]);
        q[(size_t)tt * TS_] = mem;
    }
}

__global__ __launch_bounds__(256) void scan_apply_kernel(
    const float* __restrict__ mloc, const float* __restrict__ beta_l,
    unsigned short* __restrict__ spk)
{
    const int c = blockIdx.x, b = blockIdx.y, h = threadIdx.x;
    const float bt = beta_l[h];
    float b32 = bt;
    #pragma unroll
    for (int i = 0; i < 5; ++i) b32 *= b32;        // beta^32 (CH_=32)
    float carry = 0.0f;
    for (int j = 0; j < c; ++j)
        carry = fmaf(b32, carry,
                     mloc[((size_t)(j * CH_ + CH_ - 1) * B_ + b) * H_ + h]);
    const size_t off = ((size_t)(c * CH_) * B_ + b) * H_ + h;
    const float* p = mloc + off;
    unsigned short* q = spk + off;
    float pw = bt;                                  // beta^(tt+1)
    #pragma unroll
    for (int tt = 0; tt < CH_; ++tt) {
        const float mem = fmaf(pw, carry, p[(size_t)tt * TS_]);
        pw *= bt;
        q[(size_t)tt * TS_] = (mem > 1.0f) ? (unsigned short)0x3F80u
                                           : (unsigned short)0u;
    }
}

// ---------------------------------------------------------------------------
// Small weight transpose+cast: 6x [256][256] fp32 (k-major) -> [256][256] bf16
// ---------------------------------------------------------------------------
__global__ __launch_bounds__(256) void transpose_small_kernel(
    const float* __restrict__ Wq, const float* __restrict__ Wfc,
    unsigned short* __restrict__ WT)
{
    __shared__ float t[64][65];
    const int z = blockIdx.z;
    const float* src = (z < 3) ? Wq + (size_t)z * H_ * H_
                               : Wfc + (size_t)(z - 3) * H_ * H_;
    unsigned short* dst = WT + (size_t)z * H_ * H_;
    const int n0 = blockIdx.x * 64, k0 = blockIdx.y * 64;
    const int x = threadIdx.x & 63, y = threadIdx.x >> 6;
    #pragma unroll
    for (int i = 0; i < 16; ++i)
        t[y + 4 * i][x] = src[(size_t)(k0 + y + 4 * i) * H_ + n0 + x];
    __syncthreads();
    #pragma unroll
    for (int i = 0; i < 16; ++i)
        dst[(size_t)(n0 + y + 4 * i) * H_ + k0 + x] = f2bf(t[x][y + 4 * i]);
}

// ---------------------------------------------------------------------------
// Wout [K=256][V] fp32 -> WoutT [V][K=256] bf16
// ---------------------------------------------------------------------------
__global__ __launch_bounds__(256) void transpose_wout_kernel(
    const float* __restrict__ W, unsigned short* __restrict__ Wt)
{
    __shared__ float t[64][65];
    const int n0 = blockIdx.x * 64;
    const int k0 = blockIdx.y * 64;
    const int x = threadIdx.x & 63, y = threadIdx.x >> 6;
    #pragma unroll
    for (int i = 0; i < 16; ++i)
        t[y + 4 * i][x] = W[(size_t)(k0 + y + 4 * i) * V_ + n0 + x];
    __syncthreads();
    #pragma unroll
    for (int i = 0; i < 16; ++i)
        Wt[(size_t)(n0 + y + 4 * i) * H_ + k0 + x] = f2bf(t[x][y + 4 * i]);
}

// ---------------------------------------------------------------------------
// Final projection: C[M,V] = A[M,256]bf16 @ WoutT[V,256]^T + bias, fp32 out.
// BARRIER-FREE main loop:
//   - Each block stages its 128-row Wt strip (full K=256) into LDS ONCE
//     (64 KiB, XOR-swizzled, one __syncthreads), then 4 waves independently
//     sweep 64-row m-subtiles. A-fragments load straight from global (A is
//     2 MB, L2-resident); no further barriers -> no vmcnt(0) drains.
//   - MFMA operands SWAPPED: mfma(wt, h, acc) -> D col=m(l15), row=n(quad*4+r)
//     so each lane holds 4 consecutive n -> NT global_store_dwordx4 epilogue.
// Per-CU: writes 83us (floor) >> A-from-L2 15us, LDS 13us, MFMA 8us.
// ---------------------------------------------------------------------------
__global__ __launch_bounds__(256, 2) void gemm_mfma_out(
    const unsigned short* __restrict__ A,    // [M][256] bf16
    const unsigned short* __restrict__ Bt,   // [V][256] bf16
    const float* __restrict__ bias,          // [V]
    float* __restrict__ C)
{
    constexpr int K = H_, N = V_;
    // 128 rows x 32 k-octets of 16 B = 64 KiB. Swizzle: slot for (row, oct)
    // = row*32 + ((oct & 24) | ((oct & 7) ^ (row & 7))).
    __shared__ __align__(16) short lB[4096][8];

    const int tid = threadIdx.x;
    const int lane = tid & 63, wave = tid >> 6;
    const int l15 = lane & 15, quad = lane >> 4;
    const int mh0 = blockIdx.x * 2048;            // m-half
    const int n0 = blockIdx.y * 128;              // n-strip

    // ---- stage Wt strip once: 4096 slots, 16 gl_lds groups per wave ----
    #pragma unroll
    for (int g = 0; g < 16; ++g) {
        const int base = (wave * 16 + g) * 64;
        const int s = base + lane;
        const int row = s >> 5;                           // 0..127
        const int oct = (s & 24) | ((s & 7) ^ (row & 7)); // permuted in 8-grp
        gl_lds16(Bt + (size_t)(n0 + row) * K + oct * 8, &lB[base][0]);
    }
    __syncthreads();   // ONLY barrier in the kernel

    // ---- barrier-free m-sweep: wave w handles subtiles w, w+4, ... ----
    for (int ms = wave; ms < 32; ms += 4) {
        const int m0 = mh0 + ms * 64;
        floatx4 acc[8][4] = {};
        #pragma unroll
        for (int ks = 0; ks < 8; ++ks) {                  // k = ks*32
            short8 hf[4], wf[8];
            #pragma unroll
            for (int j = 0; j < 4; ++j)
                hf[j] = *(const short8*)&A[(size_t)(m0 + j * 16 + l15) * K
                                           + ks * 32 + quad * 8];
            #pragma unroll
            for (int i = 0; i < 8; ++i) {
                const int rb = i * 16 + l15;
                const int o = ks * 4 + quad;
                const int os = (o & 24) | ((o & 7) ^ (rb & 7));
                wf[i] = *(const short8*)&lB[rb * 32 + os][0];
            }
            #pragma unroll
            for (int i = 0; i < 8; ++i)
                #pragma unroll
                for (int j = 0; j < 4; ++j)
                    acc[i][j] = __builtin_amdgcn_mfma_f32_16x16x32_bf16(
                        wf[i], hf[j], acc[i][j], 0, 0, 0);
        }
        // epilogue: D col=l15 -> m, row=quad*4+r -> n (consecutive n per lane)
        #pragma unroll
        for (int i = 0; i < 8; ++i) {
            const int n = n0 + i * 16 + quad * 4;
            const float4 bv = *(const float4*)&bias[n];
            #pragma unroll
            for (int j = 0; j < 4; ++j) {
                const int m = m0 + j * 16 + l15;
                floatx4 v;
                v[0] = acc[i][j][0] + bv.x;
                v[1] = acc[i][j][1] + bv.y;
                v[2] = acc[i][j][2] + bv.z;
                v[3] = acc[i][j][3] + bv.w;
                __builtin_nontemporal_store(v, (floatx4*)&C[(size_t)m * N + n]);
            }
        }
    }
}

// ---------------------------------------------------------------------------
// Layer GEMM: [M,256] = A[M,256]bf16 @ Bt[256,256]^T + bias, optional ReLU,
// output fp32 (for scan) or bf16 (activations). 128x64 tile, BK=64, 4 waves
// 2x2 over (64m x 32n). (Unchanged — passes, ~3 us each.)
// ---------------------------------------------------------------------------
template <int RELU, int OUT_BF16>
__global__ __launch_bounds__(256) void gemm_mfma_layer(
    const unsigned short* __restrict__ A,    // [M][256]
    const unsigned short* __restrict__ Bt,   // [256][256]
    const float* __restrict__ bias,          // [256]
    float* __restrict__ Cf, unsigned short* __restrict__ Cb)
{
    constexpr int K = H_, N = H_;
    __shared__ __align__(16) short lA[1024][8];   // 128 rows
    __shared__ __align__(16) short lB[512][8];    // 64 rows

    const int tid = threadIdx.x;
    const int lane = tid & 63, wave = tid >> 6;
    const int wm = wave >> 1, wn = wave & 1;
    const int l15 = lane & 15, quad = lane >> 4;
    const int m0 = blockIdx.x * 128;
    const int n0 = blockIdx.y * 64;

    floatx4 acc[4][2] = {};

    for (int k0 = 0; k0 < K; k0 += 64) {
        #pragma unroll
        for (int j = 0; j < 4; ++j) {
            const int base = (wave * 4 + j) * 64;
            const int s = base + lane;
            const int row = s >> 3;
            const int oct = (s & 7) ^ (row & 7);
            gl_lds16(A + (size_t)(m0 + row) * K + k0 + oct * 8, &lA[base][0]);
        }
        #pragma unroll
        for (int j = 0; j < 2; ++j) {
            const int base = (wave * 2 + j) * 64;
            const int s = base + lane;
            const int row = s >> 3;
            const int oct = (s & 7) ^ (row & 7);
            gl_lds16(Bt + (size_t)(n0 + row) * K + k0 + oct * 8, &lB[base][0]);
        }
        __syncthreads();

        #pragma unroll
        for (int t = 0; t < 2; ++t) {
            short8 af[4], bf[2];
            #pragma unroll
            for (int f = 0; f < 4; ++f) {
                const int ra = wm * 64 + f * 16 + l15;
                af[f] = *(const short8*)&lA[ra * 8 + ((4 * t + quad) ^ (ra & 7))][0];
            }
            #pragma unroll
            for (int f = 0; f < 2; ++f) {
                const int rb = wn * 32 + f * 16 + l15;
                bf[f] = *(const short8*)&lB[rb * 8 + ((4 * t + quad) ^ (rb & 7))][0];
            }
            #pragma unroll
            for (int i = 0; i < 4; ++i)
                #pragma unroll
                for (int j2 = 0; j2 < 2; ++j2)
                    acc[i][j2] = __builtin_amdgcn_mfma_f32_16x16x32_bf16(
                        af[i], bf[j2], acc[i][j2], 0, 0, 0);
        }
        __syncthreads();
    }

    #pragma unroll
    for (int j2 = 0; j2 < 2; ++j2) {
        const int col = n0 + wn * 32 + j2 * 16 + l15;
        const float bv = bias[col];
        #pragma unroll
        for (int i = 0; i < 4; ++i) {
            const int rbase = m0 + wm * 64 + i * 16 + quad * 4;
            #pragma unroll
            for (int r = 0; r < 4; ++r) {
                float v = acc[i][j2][r] + bv;
                if (RELU) v = fmaxf(v, 0.0f);
                if (OUT_BF16)
                    Cb[(size_t)(rbase + r) * N + col] = f2bf(v);
                else
                    Cf[(size_t)(rbase + r) * N + col] = v;
            }
        }
    }
}

// ---------------------------------------------------------------------------
extern "C" void kernel_launch(void* const* d_in, const int* in_sizes, int n_in,
                              void* d_out, int out_size, void* d_ws, size_t ws_size,
                              hipStream_t stream)
{
    const int*   tokens = (const int*)  d_in[0];
    const float* temb   = (const float*)d_in[1];
    const float* pemb   = (const float*)d_in[2];
    const float* Wq     = (const float*)d_in[3];
    const float* bq     = (const float*)d_in[4];
    const float* beta   = (const float*)d_in[5];
    const float* Wfc    = (const float*)d_in[6];
    const float* bfc    = (const float*)d_in[7];
    const float* Wout   = (const float*)d_in[8];
    const float* bout   = (const float*)d_in[9];
    float* out = (float*)d_out;

    // Workspace layout (all 16B-aligned): h_bf 2MB | spk 2MB | WT 0.75MB |
    // WoutT 16MB | cur 4MB | mloc 4MB
    unsigned short* h_bf  = (unsigned short*)d_ws;
    unsigned short* spk   = h_bf + (size_t)M_ * H_;
    unsigned short* WT    = spk + (size_t)M_ * H_;          // 6 x [256][256]
    unsigned short* WoutT = WT + (size_t)2 * L_ * H_ * H_;
    float*          cur   = (float*)(WoutT + (size_t)V_ * H_);
    float*          mloc  = cur + (size_t)M_ * H_;

    // Weight transposes (independent of activation pipeline)
    transpose_small_kernel<<<dim3(4, 4, 6), 256, 0, stream>>>(Wq, Wfc, WT);
    transpose_wout_kernel<<<dim3(V_ / 64, H_ / 64), 256, 0, stream>>>(Wout, WoutT);

    // 1) embed (bf16 activations)
    embed_kernel<<<(M_ * H_ / 4) / 256, 256, 0, stream>>>(tokens, temb, pemb, h_bf);

    // 2) layers: qproj (fp32 out) -> parallel scan/spike (bf16 out) -> fc (bf16)
    for (int l = 0; l < L_; ++l) {
        const unsigned short* WqT  = WT + (size_t)l * H_ * H_;
        const unsigned short* WfcT = WT + (size_t)(L_ + l) * H_ * H_;
        gemm_mfma_layer<0, 0><<<dim3(M_ / 128, H_ / 64), 256, 0, stream>>>(
            h_bf, WqT, bq + (size_t)l * H_, cur, nullptr);
        scan_local_kernel<<<dim3(NT_, B_), 256, 0, stream>>>(
            cur, beta + (size_t)l * H_, mloc);
        scan_apply_kernel<<<dim3(NT_, B_), 256, 0, stream>>>(
            mloc, beta + (size_t)l * H_, spk);
        gemm_mfma_layer<1, 1><<<dim3(M_ / 128, H_ / 64), 256, 0, stream>>>(
            spk, WfcT, bfc + (size_t)l * H_, nullptr, h_bf);
    }

    // 3) output projection: (4096 x 256) @ (256 x 32000) + bout
    gemm_mfma_out<<<dim3(M_ / 2048, V_ / 128), 256, 0, stream>>>(
        h_bf, WoutT, bout, out);
}

// Round 8
// 657.172 us; speedup vs baseline: 1.2241x; 1.2241x over previous
//
#include <hip/hip_runtime.h>
#include <hip/hip_bf16.h>
#include <cstddef>

// Problem constants (fixed by the reference)
constexpr int T_ = 512;
constexpr int B_ = 8;
constexpr int H_ = 256;
constexpr int V_ = 32000;
constexpr int L_ = 3;
constexpr int M_ = T_ * B_;   // 4096 rows in all GEMMs

typedef __attribute__((ext_vector_type(8))) short short8;
typedef __attribute__((ext_vector_type(4))) float floatx4;

// fp32 -> bf16 round-to-nearest-even
__device__ __forceinline__ unsigned short f2bf(float f) {
    unsigned u = __float_as_uint(f);
    u += 0x7fffu + ((u >> 16) & 1u);
    return (unsigned short)(u >> 16);
}

// async global->LDS, 16B per lane; LDS dest = wave-uniform base + lane*16
__device__ __forceinline__ void gl_lds16(const void* g, void* l) {
    __builtin_amdgcn_global_load_lds((__attribute__((address_space(1))) void*)g,
                                     (__attribute__((address_space(3))) void*)l,
                                     16, 0, 0);
}

// ---------------------------------------------------------------------------
// Embed: h_bf[t,b,:] = bf16(token_emb[tokens[t,b],:] + pos_emb[t,:])
// ---------------------------------------------------------------------------
__global__ __launch_bounds__(256) void embed_kernel(
    const int* __restrict__ tokens, const float* __restrict__ temb,
    const float* __restrict__ pemb, unsigned short* __restrict__ hb)
{
    const int idx = blockIdx.x * 256 + threadIdx.x;      // 0 .. T*B*H/4-1
    const int h4 = idx & (H_ / 4 - 1);
    const int tb = idx >> 6;
    const int b  = tb & (B_ - 1);
    const int t  = tb >> 3;
    const int tok = tokens[t * B_ + b];
    const float4 e = *(const float4*)&temb[(size_t)tok * H_ + h4 * 4];
    const float4 p = *(const float4*)&pemb[(size_t)t * H_ + h4 * 4];
    ushort4 r;
    r.x = f2bf(e.x + p.x); r.y = f2bf(e.y + p.y);
    r.z = f2bf(e.z + p.z); r.w = f2bf(e.w + p.w);
    *(ushort4*)&hb[(size_t)idx * 4] = r;
}

// ===========================================================================
// Parallel chunked leaky scan (linear recurrence; chunk-local + carry apply).
// Spike margin ~0.9 vs the ~1e-7 reordering delta -> no spike flips.
// ===========================================================================
constexpr int CH_ = 32;
constexpr int NT_ = T_ / CH_;          // 16 chunks
constexpr int TS_ = B_ * H_;           // 2048: t-stride in [T][B][H]

__global__ __launch_bounds__(256) void scan_local_kernel(
    const float* __restrict__ cur, const float* __restrict__ beta_l,
    float* __restrict__ mloc)
{
    const int c = blockIdx.x, b = blockIdx.y, h = threadIdx.x;
    const float bt = beta_l[h];
    const size_t off = ((size_t)(c * CH_) * B_ + b) * H_ + h;
    const float* p = cur + off;
    float* q = mloc + off;
    float mem = 0.0f;
    #pragma unroll
    for (int tt = 0; tt < CH_; ++tt) {
        mem = fmaf(bt, mem, p[(size_t)tt * TS_]);
        q[(size_t)tt * TS_] = mem;
    }
}

__global__ __launch_bounds__(256) void scan_apply_kernel(
    const float* __restrict__ mloc, const float* __restrict__ beta_l,
    unsigned short* __restrict__ spk)
{
    const int c = blockIdx.x, b = blockIdx.y, h = threadIdx.x;
    const float bt = beta_l[h];
    float b32 = bt;
    #pragma unroll
    for (int i = 0; i < 5; ++i) b32 *= b32;        // beta^32 (CH_=32)
    float carry = 0.0f;
    for (int j = 0; j < c; ++j)
        carry = fmaf(b32, carry,
                     mloc[((size_t)(j * CH_ + CH_ - 1) * B_ + b) * H_ + h]);
    const size_t off = ((size_t)(c * CH_) * B_ + b) * H_ + h;
    const float* p = mloc + off;
    unsigned short* q = spk + off;
    float pw = bt;                                  // beta^(tt+1)
    #pragma unroll
    for (int tt = 0; tt < CH_; ++tt) {
        const float mem = fmaf(pw, carry, p[(size_t)tt * TS_]);
        pw *= bt;
        q[(size_t)tt * TS_] = (mem > 1.0f) ? (unsigned short)0x3F80u
                                           : (unsigned short)0u;
    }
}

// ---------------------------------------------------------------------------
// Small weight transpose+cast: 6x [256][256] fp32 (k-major) -> [256][256] bf16
// ---------------------------------------------------------------------------
__global__ __launch_bounds__(256) void transpose_small_kernel(
    const float* __restrict__ Wq, const float* __restrict__ Wfc,
    unsigned short* __restrict__ WT)
{
    __shared__ float t[64][65];
    const int z = blockIdx.z;
    const float* src = (z < 3) ? Wq + (size_t)z * H_ * H_
                               : Wfc + (size_t)(z - 3) * H_ * H_;
    unsigned short* dst = WT + (size_t)z * H_ * H_;
    const int n0 = blockIdx.x * 64, k0 = blockIdx.y * 64;
    const int x = threadIdx.x & 63, y = threadIdx.x >> 6;
    #pragma unroll
    for (int i = 0; i < 16; ++i)
        t[y + 4 * i][x] = src[(size_t)(k0 + y + 4 * i) * H_ + n0 + x];
    __syncthreads();
    #pragma unroll
    for (int i = 0; i < 16; ++i)
        dst[(size_t)(n0 + y + 4 * i) * H_ + k0 + x] = f2bf(t[x][y + 4 * i]);
}

// ---------------------------------------------------------------------------
// Wout [K=256][V] fp32 -> WoutT [V][K=256] bf16
// ---------------------------------------------------------------------------
__global__ __launch_bounds__(256) void transpose_wout_kernel(
    const float* __restrict__ W, unsigned short* __restrict__ Wt)
{
    __shared__ float t[64][65];
    const int n0 = blockIdx.x * 64;
    const int k0 = blockIdx.y * 64;
    const int x = threadIdx.x & 63, y = threadIdx.x >> 6;
    #pragma unroll
    for (int i = 0; i < 16; ++i)
        t[y + 4 * i][x] = W[(size_t)(k0 + y + 4 * i) * V_ + n0 + x];
    __syncthreads();
    #pragma unroll
    for (int i = 0; i < 16; ++i)
        Wt[(size_t)(n0 + y + 4 * i) * H_ + k0 + x] = f2bf(t[x][y + 4 * i]);
}

// ===========================================================================
// XOR-swizzled LDS staging scheme (all MFMA GEMMs):
//   chunk = 16 B = 8 bf16 = one k-octet. Row of a BK=64 tile = 8 octets.
//   Slot for (row, oct):  s = row*8 + (oct ^ (row & 7)),  LDS byte addr s*16.
//   global_load_lds groups of 64 slots = 8 rows x 8 permuted octets
//   = 8 x 128 B coalesced line reads; fragment ds_read_b128 spreads uniformly
//   over all 32 banks (2-way max aliasing = free per m136).
// ===========================================================================

// ---------------------------------------------------------------------------
// Final projection: C[M,V] = A[M,256]bf16 @ WoutT[V,256]^T + bias, fp32 out.
// R5 K-loop (256m x 128n block, 4 waves 2x2, wave-tile 128x64) + NEW epilogue:
// each wave routes its C-tile through a private LDS scratch (16x68 fp32)
// 16 rows at a time, then emits NT float4 stores in FULL 256-B-contiguous
// row segments (4 rows x 256 B per instr). NT bypasses L2 so the 524 MB
// C stream cannot evict A/Wt (reads stay L2-resident); full-line segments
// avoid partial-line write penalties.
// ---------------------------------------------------------------------------
__global__ __launch_bounds__(256, 2) void gemm_mfma_out(
    const unsigned short* __restrict__ A,    // [M][256] bf16
    const unsigned short* __restrict__ Bt,   // [V][256] bf16
    const float* __restrict__ bias,          // [V]
    float* __restrict__ C)
{
    constexpr int K = H_, N = V_;
    __shared__ __align__(16) short lA[2048][8];   // 32 KiB: 256 rows x 8 octets
    __shared__ __align__(16) short lB[1024][8];   // 16 KiB: 128 rows

    const int tid = threadIdx.x;
    const int lane = tid & 63, wave = tid >> 6;
    const int wm = wave >> 1, wn = wave & 1;     // wave-tile: 128m x 64n
    const int l15 = lane & 15, quad = lane >> 4;
    const int m0 = blockIdx.x * 256;             // x = m (fast): 16 blocks/n-tile
    const int n0 = blockIdx.y * 128;

    floatx4 acc[8][4] = {};

    for (int k0 = 0; k0 < K; k0 += 64) {
        // stage A: 256 rows x 8 octets = 2048 slots
        #pragma unroll
        for (int j = 0; j < 8; ++j) {
            const int base = (wave * 8 + j) * 64;
            const int s = base + lane;
            const int row = s >> 3;
            const int oct = (s & 7) ^ (row & 7);
            gl_lds16(A + (size_t)(m0 + row) * K + k0 + oct * 8, &lA[base][0]);
        }
        // stage B: 128 rows = 1024 slots
        #pragma unroll
        for (int j = 0; j < 4; ++j) {
            const int base = (wave * 4 + j) * 64;
            const int s = base + lane;
            const int row = s >> 3;
            const int oct = (s & 7) ^ (row & 7);
            gl_lds16(Bt + (size_t)(n0 + row) * K + k0 + oct * 8, &lB[base][0]);
        }
        __syncthreads();

        #pragma unroll
        for (int t = 0; t < 2; ++t) {
            short8 af[8], bf[4];
            #pragma unroll
            for (int f = 0; f < 8; ++f) {
                const int ra = wm * 128 + f * 16 + l15;
                af[f] = *(const short8*)&lA[ra * 8 + ((4 * t + quad) ^ (ra & 7))][0];
            }
            #pragma unroll
            for (int g = 0; g < 4; ++g) {
                const int rb = wn * 64 + g * 16 + l15;
                bf[g] = *(const short8*)&lB[rb * 8 + ((4 * t + quad) ^ (rb & 7))][0];
            }
            #pragma unroll
            for (int f = 0; f < 8; ++f)
                #pragma unroll
                for (int g = 0; g < 4; ++g)
                    acc[f][g] = __builtin_amdgcn_mfma_f32_16x16x32_bf16(
                        af[f], bf[g], acc[f][g], 0, 0, 0);
        }
        __syncthreads();
    }

    // ---- epilogue via per-wave LDS scratch -> full-line NT stores ----
    // D layout per frag: col(n) = l15, row(m) = quad*4 + r (m89/m91-verified).
    float* scr = (float*)&lA[0][0] + (size_t)wave * 1088;   // 16 x 68 fp32
    float bvv[4];
    #pragma unroll
    for (int g = 0; g < 4; ++g)
        bvv[g] = bias[n0 + wn * 64 + g * 16 + l15];

    #pragma unroll
    for (int f = 0; f < 8; ++f) {
        // scatter this 16-row chunk (m-local x 64 n-local) into scratch
        #pragma unroll
        for (int g = 0; g < 4; ++g)
            #pragma unroll
            for (int r = 0; r < 4; ++r)
                scr[(quad * 4 + r) * 68 + g * 16 + l15] = acc[f][g][r] + bvv[g];
        __syncthreads();   // uniform: orders LDS writes before reads
        // gather row-major: 4 instrs x (4 rows x 256 B contiguous)
        #pragma unroll
        for (int rr = 0; rr < 4; ++rr) {
            const int ml = rr * 4 + quad;
            const floatx4 v = *(const floatx4*)&scr[ml * 68 + l15 * 4];
            const size_t m = (size_t)(m0 + wm * 128 + f * 16 + ml);
            __builtin_nontemporal_store(
                v, (floatx4*)&C[m * (size_t)N + n0 + wn * 64 + l15 * 4]);
        }
        __syncthreads();   // reads done before next chunk overwrites
    }
}

// ---------------------------------------------------------------------------
// Layer GEMM: [M,256] = A[M,256]bf16 @ Bt[256,256]^T + bias, optional ReLU,
// output fp32 (for scan) or bf16 (activations). 128x64 tile, BK=64, 4 waves
// 2x2 over (64m x 32n). (Unchanged — passes, ~3 us each.)
// ---------------------------------------------------------------------------
template <int RELU, int OUT_BF16>
__global__ __launch_bounds__(256) void gemm_mfma_layer(
    const unsigned short* __restrict__ A,    // [M][256]
    const unsigned short* __restrict__ Bt,   // [256][256]
    const float* __restrict__ bias,          // [256]
    float* __restrict__ Cf, unsigned short* __restrict__ Cb)
{
    constexpr int K = H_, N = H_;
    __shared__ __align__(16) short lA[1024][8];   // 128 rows
    __shared__ __align__(16) short lB[512][8];    // 64 rows

    const int tid = threadIdx.x;
    const int lane = tid & 63, wave = tid >> 6;
    const int wm = wave >> 1, wn = wave & 1;
    const int l15 = lane & 15, quad = lane >> 4;
    const int m0 = blockIdx.x * 128;
    const int n0 = blockIdx.y * 64;

    floatx4 acc[4][2] = {};

    for (int k0 = 0; k0 < K; k0 += 64) {
        #pragma unroll
        for (int j = 0; j < 4; ++j) {
            const int base = (wave * 4 + j) * 64;
            const int s = base + lane;
            const int row = s >> 3;
            const int oct = (s & 7) ^ (row & 7);
            gl_lds16(A + (size_t)(m0 + row) * K + k0 + oct * 8, &lA[base][0]);
        }
        #pragma unroll
        for (int j = 0; j < 2; ++j) {
            const int base = (wave * 2 + j) * 64;
            const int s = base + lane;
            const int row = s >> 3;
            const int oct = (s & 7) ^ (row & 7);
            gl_lds16(Bt + (size_t)(n0 + row) * K + k0 + oct * 8, &lB[base][0]);
        }
        __syncthreads();

        #pragma unroll
        for (int t = 0; t < 2; ++t) {
            short8 af[4], bf[2];
            #pragma unroll
            for (int f = 0; f < 4; ++f) {
                const int ra = wm * 64 + f * 16 + l15;
                af[f] = *(const short8*)&lA[ra * 8 + ((4 * t + quad) ^ (ra & 7))][0];
            }
            #pragma unroll
            for (int f = 0; f < 2; ++f) {
                const int rb = wn * 32 + f * 16 + l15;
                bf[f] = *(const short8*)&lB[rb * 8 + ((4 * t + quad) ^ (rb & 7))][0];
            }
            #pragma unroll
            for (int i = 0; i < 4; ++i)
                #pragma unroll
                for (int j2 = 0; j2 < 2; ++j2)
                    acc[i][j2] = __builtin_amdgcn_mfma_f32_16x16x32_bf16(
                        af[i], bf[j2], acc[i][j2], 0, 0, 0);
        }
        __syncthreads();
    }

    #pragma unroll
    for (int j2 = 0; j2 < 2; ++j2) {
        const int col = n0 + wn * 32 + j2 * 16 + l15;
        const float bv = bias[col];
        #pragma unroll
        for (int i = 0; i < 4; ++i) {
            const int rbase = m0 + wm * 64 + i * 16 + quad * 4;
            #pragma unroll
            for (int r = 0; r < 4; ++r) {
                float v = acc[i][j2][r] + bv;
                if (RELU) v = fmaxf(v, 0.0f);
                if (OUT_BF16)
                    Cb[(size_t)(rbase + r) * N + col] = f2bf(v);
                else
                    Cf[(size_t)(rbase + r) * N + col] = v;
            }
        }
    }
}

// ---------------------------------------------------------------------------
extern "C" void kernel_launch(void* const* d_in, const int* in_sizes, int n_in,
                              void* d_out, int out_size, void* d_ws, size_t ws_size,
                              hipStream_t stream)
{
    const int*   tokens = (const int*)  d_in[0];
    const float* temb   = (const float*)d_in[1];
    const float* pemb   = (const float*)d_in[2];
    const float* Wq     = (const float*)d_in[3];
    const float* bq     = (const float*)d_in[4];
    const float* beta   = (const float*)d_in[5];
    const float* Wfc    = (const float*)d_in[6];
    const float* bfc    = (const float*)d_in[7];
    const float* Wout   = (const float*)d_in[8];
    const float* bout   = (const float*)d_in[9];
    float* out = (float*)d_out;

    // Workspace layout (all 16B-aligned): h_bf 2MB | spk 2MB | WT 0.75MB |
    // WoutT 16MB | cur 4MB | mloc 4MB
    unsigned short* h_bf  = (unsigned short*)d_ws;
    unsigned short* spk   = h_bf + (size_t)M_ * H_;
    unsigned short* WT    = spk + (size_t)M_ * H_;          // 6 x [256][256]
    unsigned short* WoutT = WT + (size_t)2 * L_ * H_ * H_;
    float*          cur   = (float*)(WoutT + (size_t)V_ * H_);
    float*          mloc  = cur + (size_t)M_ * H_;

    // Weight transposes (independent of activation pipeline)
    transpose_small_kernel<<<dim3(4, 4, 6), 256, 0, stream>>>(Wq, Wfc, WT);
    transpose_wout_kernel<<<dim3(V_ / 64, H_ / 64), 256, 0, stream>>>(Wout, WoutT);

    // 1) embed (bf16 activations)
    embed_kernel<<<(M_ * H_ / 4) / 256, 256, 0, stream>>>(tokens, temb, pemb, h_bf);

    // 2) layers: qproj (fp32 out) -> parallel scan/spike (bf16 out) -> fc (bf16)
    for (int l = 0; l < L_; ++l) {
        const unsigned short* WqT  = WT + (size_t)l * H_ * H_;
        const unsigned short* WfcT = WT + (size_t)(L_ + l) * H_ * H_;
        gemm_mfma_layer<0, 0><<<dim3(M_ / 128, H_ / 64), 256, 0, stream>>>(
            h_bf, WqT, bq + (size_t)l * H_, cur, nullptr);
        scan_local_kernel<<<dim3(NT_, B_), 256, 0, stream>>>(
            cur, beta + (size_t)l * H_, mloc);
        scan_apply_kernel<<<dim3(NT_, B_), 256, 0, stream>>>(
            mloc, beta + (size_t)l * H_, spk);
        gemm_mfma_layer<1, 1><<<dim3(M_ / 128, H_ / 64), 256, 0, stream>>>(
            spk, WfcT, bfc + (size_t)l * H_, nullptr, h_bf);
    }

    // 3) output projection: (4096 x 256) @ (256 x 32000) + bout
    gemm_mfma_out<<<dim3(M_ / 256, V_ / 128), 256, 0, stream>>>(
        h_bf, WoutT, bout, out);
}